// Round 8
// baseline (595.733 us; speedup 1.0000x reference)
//
#include <hip/hip_runtime.h>
#include <hip/hip_bf16.h>
#include <math.h>

#define NN 50000
#define EE 640000
#define DD 128
#define NREL 8
#define NCLS 16
#define NBUCK (NREL * NN)              // 400000 buckets, key = rel*NN + dst
#define SCAN_NB ((NBUCK + 255) / 256)  // 1563
#define NBIN 64

typedef __attribute__((ext_vector_type(8))) short short8;   // 8 bf16 = 4 VGPRs
typedef __attribute__((ext_vector_type(4))) float f32x4;    // MFMA acc

__device__ __forceinline__ float bflo(unsigned u) { return __uint_as_float(u << 16); }
__device__ __forceinline__ float bfhi(unsigned u) { return __uint_as_float(u & 0xffff0000u); }
__device__ __forceinline__ float bf2f(ushort u) { return __uint_as_float(((unsigned)u) << 16); }
__device__ __forceinline__ ushort f2b(float f) {  // RNE
  unsigned u = __float_as_uint(f);
  u += 0x7fff + ((u >> 16) & 1);
  return (ushort)(u >> 16);
}

// ---------- CSR build (key = rel*NN + dst) ----------

__global__ __launch_bounds__(256) void count_kernel(const int* __restrict__ ei,
                                                    const int* __restrict__ et,
                                                    int* __restrict__ cnt) {
  int t = blockIdx.x * 256 + threadIdx.x;
  if (t < EE) {
    int key = et[t] * NN + ei[EE + t];
    atomicAdd(&cnt[key], 1);
  }
}

__global__ __launch_bounds__(256) void scan1_kernel(const int* __restrict__ cnt,
                                                    int* __restrict__ off,
                                                    int* __restrict__ bsum) {
  __shared__ int s[256];
  const int tid = threadIdx.x;
  const int i = blockIdx.x * 256 + tid;
  int v = (i < NBUCK) ? cnt[i] : 0;
  s[tid] = v;
  __syncthreads();
#pragma unroll
  for (int o = 1; o < 256; o <<= 1) {
    int t2 = (tid >= o) ? s[tid - o] : 0;
    __syncthreads();
    s[tid] += t2;
    __syncthreads();
  }
  if (i < NBUCK) off[i] = s[tid] - v;
  if (tid == 255) bsum[blockIdx.x] = s[255];
}

__global__ __launch_bounds__(256) void scan2_kernel(const int* __restrict__ bsum,
                                                    int* __restrict__ bpre) {
  __shared__ int s[256];
  __shared__ int carry;
  const int tid = threadIdx.x;
  if (tid == 0) carry = 0;
  __syncthreads();
  const int chunks = (SCAN_NB + 255) / 256;
  for (int c = 0; c < chunks; c++) {
    int idx = c * 256 + tid;
    int v = (idx < SCAN_NB) ? bsum[idx] : 0;
    s[tid] = v;
    __syncthreads();
#pragma unroll
    for (int o = 1; o < 256; o <<= 1) {
      int t2 = (tid >= o) ? s[tid - o] : 0;
      __syncthreads();
      s[tid] += t2;
      __syncthreads();
    }
    if (idx < SCAN_NB) bpre[idx] = carry + s[tid] - v;
    __syncthreads();
    if (tid == 255) carry += s[255];
    __syncthreads();
  }
}

// finalizes off, fills cursor, zeroes the bin histogram
__global__ __launch_bounds__(256) void scan3_kernel(int* __restrict__ off,
                                                    const int* __restrict__ bpre,
                                                    int* __restrict__ cursor,
                                                    int* __restrict__ hist) {
  int i = blockIdx.x * 256 + threadIdx.x;
  if (i < NBUCK) {
    int o = off[i] + bpre[i >> 8];
    off[i] = o;
    cursor[i] = o;
  }
  if (i < NBIN) hist[i] = 0;
  if (i == 0) off[NBUCK] = EE;
}

// rec = (src, raw edge weight); mean divisor = bucket length at use
__global__ __launch_bounds__(256) void bucket_kernel(const int* __restrict__ ei,
                                                     const int* __restrict__ et,
                                                     const float* __restrict__ ew,
                                                     int* __restrict__ cursor,
                                                     uint2* __restrict__ rec) {
  int e = blockIdx.x * 256 + threadIdx.x;
  if (e >= EE) return;
  int key = et[e] * NN + ei[EE + e];
  int pos = atomicAdd(&cursor[key], 1);
  rec[pos] = make_uint2((unsigned)ei[e], __float_as_uint(ew[e]));
}

// ---------- bucket-length counting sort -> queue ----------

__global__ __launch_bounds__(256) void hist_kernel(const int* __restrict__ cnt,
                                                   int* __restrict__ hist) {
  __shared__ int lh[NBIN];
  const int tid = threadIdx.x;
  if (tid < NBIN) lh[tid] = 0;
  __syncthreads();
  int i = blockIdx.x * 256 + tid;
  if (i < NBUCK) atomicAdd(&lh[min(cnt[i], NBIN - 1)], 1);
  __syncthreads();
  if (tid < NBIN && lh[tid] > 0) atomicAdd(&hist[tid], lh[tid]);
}

// exclusive scan of the 64-bin histogram -> binCur (single block)
__global__ __launch_bounds__(256) void scan64_kernel(const int* __restrict__ hist,
                                                     int* __restrict__ binCur) {
  __shared__ int s[NBIN];
  const int tid = threadIdx.x;
  if (tid < NBIN) s[tid] = hist[tid];
  __syncthreads();
#pragma unroll
  for (int o = 1; o < NBIN; o <<= 1) {
    int t2 = (tid < NBIN && tid >= o) ? s[tid - o] : 0;
    __syncthreads();
    if (tid < NBIN) s[tid] += t2;
    __syncthreads();
  }
  if (tid < NBIN) binCur[tid] = s[tid] - hist[tid];
}

// scatter bucket ids into length-sorted queue (LDS-batched cursor allocation)
__global__ __launch_bounds__(256) void qbuild_kernel(const int* __restrict__ cnt,
                                                     int* __restrict__ binCur,
                                                     int* __restrict__ queue) {
  __shared__ int lh[NBIN];
  __shared__ int lbase[NBIN];
  const int tid = threadIdx.x;
  const int i = blockIdx.x * 256 + tid;
  int bin = -1, lpos = 0;
  if (tid < NBIN) lh[tid] = 0;
  __syncthreads();
  if (i < NBUCK) {
    bin = min(cnt[i], NBIN - 1);
    lpos = atomicAdd(&lh[bin], 1);
  }
  __syncthreads();
  if (tid < NBIN && lh[tid] > 0) lbase[tid] = atomicAdd(&binCur[tid], lh[tid]);
  __syncthreads();
  if (bin >= 0) queue[lbase[bin] + lpos] = i;
}

// ---------- pack x (bf16) + W1Tc + W2T ----------
// W1Tc[n*1024 + r*128 + k] = bf16(W1[r][k][n]); W2T[j*128 + k] = bf16(W2[j>>4][k][j&15])
#define XQ (NN * DD / 4)
__global__ __launch_bounds__(256) void pack_kernel(const float* __restrict__ x,
                                                   const float* __restrict__ W1,
                                                   const float* __restrict__ W2,
                                                   ushort* __restrict__ xb,
                                                   ushort* __restrict__ W1Tc,
                                                   ushort* __restrict__ W2T) {
  int t = blockIdx.x * 256 + threadIdx.x;
  if (t < XQ) {
    float4 v = *(const float4*)&x[(size_t)t * 4];
    *(ushort4*)&xb[(size_t)t * 4] = make_ushort4(f2b(v.x), f2b(v.y), f2b(v.z), f2b(v.w));
  } else if (t < XQ + NREL * DD * DD) {
    int t2 = t - XQ;
    int n = t2 >> 10, r = (t2 >> 7) & 7, k = t2 & 127;
    W1Tc[t2] = f2b(W1[r * 16384 + k * 128 + n]);
  } else if (t < XQ + NREL * DD * DD + DD * DD) {
    int t2 = t - XQ - NREL * DD * DD;
    int j = t2 >> 7, k = t2 & 127;
    W2T[t2] = f2b(W2[(j >> 4) * (DD * NCLS) + k * NCLS + (j & 15)]);
  }
}

// ---------- gather1: length-sorted queue, 4 threads/bucket x 32 cols ----------
// Agg[v*1024 + r*128 + c] = bf16( sum_bucket (ew/cnt) * xb[src][c] )
__global__ __launch_bounds__(256) void gather1_kernel(const int* __restrict__ off,
                                                      const uint2* __restrict__ rec,
                                                      const ushort* __restrict__ xb,
                                                      const int* __restrict__ queue,
                                                      ushort* __restrict__ Agg) {
  const int b = queue[blockIdx.x * 64 + (threadIdx.x >> 2)];
  const int cq = (threadIdx.x & 3) * 32;
  const int r = b / NN, v = b - r * NN;
  const int s = off[b], e = off[b + 1];
  const float inv = 1.0f / fmaxf((float)(e - s), 1.0f);
  float g[32];
#pragma unroll
  for (int j = 0; j < 32; j++) g[j] = 0.f;
  for (int i = s; i < e; i++) {
    uint2 q = rec[i];
    float sc = __uint_as_float(q.y) * inv;
    const ushort* xr = &xb[(size_t)q.x * DD + cq];
#pragma unroll
    for (int jj = 0; jj < 4; jj++) {
      uint4 h = *(const uint4*)&xr[jj * 8];
      float* gg = &g[jj * 8];
      gg[0] = fmaf(sc, bflo(h.x), gg[0]);
      gg[1] = fmaf(sc, bfhi(h.x), gg[1]);
      gg[2] = fmaf(sc, bflo(h.y), gg[2]);
      gg[3] = fmaf(sc, bfhi(h.y), gg[3]);
      gg[4] = fmaf(sc, bflo(h.z), gg[4]);
      gg[5] = fmaf(sc, bfhi(h.z), gg[5]);
      gg[6] = fmaf(sc, bflo(h.w), gg[6]);
      gg[7] = fmaf(sc, bfhi(h.w), gg[7]);
    }
  }
  ushort* op = &Agg[(size_t)v * 1024 + r * 128 + cq];
#pragma unroll
  for (int jj = 0; jj < 4; jj++) {
    uint4 u;
    u.x = (unsigned)f2b(g[jj * 8 + 0]) | ((unsigned)f2b(g[jj * 8 + 1]) << 16);
    u.y = (unsigned)f2b(g[jj * 8 + 2]) | ((unsigned)f2b(g[jj * 8 + 3]) << 16);
    u.z = (unsigned)f2b(g[jj * 8 + 4]) | ((unsigned)f2b(g[jj * 8 + 5]) << 16);
    u.w = (unsigned)f2b(g[jj * 8 + 6]) | ((unsigned)f2b(g[jj * 8 + 7]) << 16);
    *(uint4*)&op[jj * 8] = u;
  }
}

// ---------- gemmfused: H2 = bf16( relu(Agg @ W1Tc^T) @ W2T^T ) ----------
// Block = 64 nodes, K=1024 in 8 chunks; stage->sync->MFMA (no reg-hold across barrier).
__global__ __launch_bounds__(256) void gemmfused_kernel(const ushort* __restrict__ Agg,
                                                        const ushort* __restrict__ W1Tc,
                                                        const ushort* __restrict__ W2T,
                                                        ushort* __restrict__ H2) {
  __shared__ ushort AsU[64 * 136];     // 17408 B
  __shared__ ushort Bs[128 * 136];     // 34816 B
  const int tid = threadIdx.x;
  const int m0 = blockIdx.x * 64;
  const int wave = tid >> 6, lane = tid & 63;
  const int lm = lane & 15, lkb = (lane >> 4) * 8;

  f32x4 acc[4][2];
#pragma unroll
  for (int m = 0; m < 4; m++)
#pragma unroll
    for (int j = 0; j < 2; j++) acc[m][j] = (f32x4){0.f, 0.f, 0.f, 0.f};

  for (int ch = 0; ch < 8; ch++) {
    __syncthreads();  // previous chunk's LDS reads complete
#pragma unroll
    for (int i = 0; i < 8; i++) {
      int seg = tid + i * 256;
      int row = seg >> 4, c8 = (seg & 15) * 8;
      *(uint4*)&Bs[row * 136 + c8] =
          *(const uint4*)&W1Tc[(size_t)row * 1024 + ch * 128 + c8];
    }
#pragma unroll
    for (int i = 0; i < 4; i++) {
      int seg = tid + i * 256;
      int row = seg >> 4, c8 = (seg & 15) * 8;
      int gr = m0 + row;
      uint4 va = make_uint4(0u, 0u, 0u, 0u);
      if (gr < NN) va = *(const uint4*)&Agg[(size_t)gr * 1024 + ch * 128 + c8];
      *(uint4*)&AsU[row * 136 + c8] = va;
    }
    __syncthreads();
#pragma unroll
    for (int k0 = 0; k0 < 128; k0 += 32) {
      short8 a[4];
#pragma unroll
      for (int m = 0; m < 4; m++)
        a[m] = *(const short8*)&AsU[(m * 16 + lm) * 136 + k0 + lkb];
#pragma unroll
      for (int j = 0; j < 2; j++) {
        short8 b = *(const short8*)&Bs[((wave * 2 + j) * 16 + lm) * 136 + k0 + lkb];
#pragma unroll
        for (int m = 0; m < 4; m++)
          acc[m][j] = __builtin_amdgcn_mfma_f32_16x16x32_bf16(a[m], b, acc[m][j], 0, 0, 0);
      }
    }
  }

  // epilogue 1: relu -> bf16 A2 tile in LDS
  __syncthreads();
  const int rquad = (lane >> 4) * 4;
#pragma unroll
  for (int m = 0; m < 4; m++)
#pragma unroll
    for (int j = 0; j < 2; j++)
#pragma unroll
      for (int i = 0; i < 4; i++)
        AsU[(m * 16 + rquad + i) * 136 + wave * 32 + j * 16 + lm] =
            f2b(fmaxf(acc[m][j][i], 0.f));
  __syncthreads();

  // layer-2 GEMM on the in-LDS A2 tile
#pragma unroll
  for (int i = 0; i < 8; i++) {
    int seg = tid + i * 256;
    int row = seg >> 4, c8 = (seg & 15) * 8;
    *(uint4*)&Bs[row * 136 + c8] = *(const uint4*)&W2T[(size_t)row * DD + c8];
  }
  __syncthreads();
  f32x4 acc2[4][2];
#pragma unroll
  for (int m = 0; m < 4; m++)
#pragma unroll
    for (int j = 0; j < 2; j++) acc2[m][j] = (f32x4){0.f, 0.f, 0.f, 0.f};
#pragma unroll
  for (int k0 = 0; k0 < 128; k0 += 32) {
    short8 a[4];
#pragma unroll
    for (int m = 0; m < 4; m++)
      a[m] = *(const short8*)&AsU[(m * 16 + lm) * 136 + k0 + lkb];
#pragma unroll
    for (int j = 0; j < 2; j++) {
      short8 b = *(const short8*)&Bs[((wave * 2 + j) * 16 + lm) * 136 + k0 + lkb];
#pragma unroll
      for (int m = 0; m < 4; m++)
        acc2[m][j] = __builtin_amdgcn_mfma_f32_16x16x32_bf16(a[m], b, acc2[m][j], 0, 0, 0);
    }
  }
  __syncthreads();
#pragma unroll
  for (int m = 0; m < 4; m++)
#pragma unroll
    for (int j = 0; j < 2; j++)
#pragma unroll
      for (int i = 0; i < 4; i++)
        AsU[(m * 16 + rquad + i) * 136 + wave * 32 + j * 16 + lm] = f2b(acc2[m][j][i]);
  __syncthreads();
#pragma unroll
  for (int i = 0; i < 4; i++) {
    int seg = tid + i * 256;
    int row = seg >> 4, c8 = (seg & 15) * 8;
    int gr = m0 + row;
    if (gr < NN) *(uint4*)&H2[(size_t)gr * DD + c8] = *(const uint4*)&AsU[row * 136 + c8];
  }
}

// ---------- gather2: thread-per-bucket from queue; 16 fp32 acc + atomic out ----------
__global__ __launch_bounds__(256) void gather2_kernel(const int* __restrict__ off,
                                                      const uint2* __restrict__ rec,
                                                      const ushort* __restrict__ H2,
                                                      const int* __restrict__ queue,
                                                      float* __restrict__ out) {
  int i = blockIdx.x * 256 + threadIdx.x;
  if (i >= NBUCK) return;
  const int b = queue[i];
  const int s = off[b], e = off[b + 1];
  if (e == s) return;
  const int r = b / NN, v = b - r * NN;
  const float inv = 1.0f / (float)(e - s);
  float o[16];
#pragma unroll
  for (int c = 0; c < 16; c++) o[c] = 0.f;
  for (int j = s; j < e; j++) {
    uint2 q = rec[j];
    float sc = __uint_as_float(q.y) * inv;
    const ushort* hp = &H2[(size_t)q.x * DD + r * NCLS];
    uint4 h0 = *(const uint4*)hp;
    uint4 h1 = *(const uint4*)(hp + 8);
    o[0]  = fmaf(sc, bflo(h0.x), o[0]);
    o[1]  = fmaf(sc, bfhi(h0.x), o[1]);
    o[2]  = fmaf(sc, bflo(h0.y), o[2]);
    o[3]  = fmaf(sc, bfhi(h0.y), o[3]);
    o[4]  = fmaf(sc, bflo(h0.z), o[4]);
    o[5]  = fmaf(sc, bfhi(h0.z), o[5]);
    o[6]  = fmaf(sc, bflo(h0.w), o[6]);
    o[7]  = fmaf(sc, bfhi(h0.w), o[7]);
    o[8]  = fmaf(sc, bflo(h1.x), o[8]);
    o[9]  = fmaf(sc, bfhi(h1.x), o[9]);
    o[10] = fmaf(sc, bflo(h1.y), o[10]);
    o[11] = fmaf(sc, bfhi(h1.y), o[11]);
    o[12] = fmaf(sc, bflo(h1.z), o[12]);
    o[13] = fmaf(sc, bfhi(h1.z), o[13]);
    o[14] = fmaf(sc, bflo(h1.w), o[14]);
    o[15] = fmaf(sc, bfhi(h1.w), o[15]);
  }
  float* op = &out[(size_t)v * NCLS];
#pragma unroll
  for (int c = 0; c < 16; c++) unsafeAtomicAdd(&op[c], o[c]);
}

// ---------- log_softmax in place ----------
__global__ __launch_bounds__(256) void lsm_kernel(float* __restrict__ out) {
  int t = blockIdx.x * 256 + threadIdx.x;
  if (t >= NN) return;
  float v[16];
#pragma unroll
  for (int i = 0; i < 4; i++) {
    float4 q = *(const float4*)&out[t * 16 + i * 4];
    v[i * 4 + 0] = q.x; v[i * 4 + 1] = q.y;
    v[i * 4 + 2] = q.z; v[i * 4 + 3] = q.w;
  }
  float m = v[0];
#pragma unroll
  for (int i = 1; i < 16; i++) m = fmaxf(m, v[i]);
  float s = 0.f;
#pragma unroll
  for (int i = 0; i < 16; i++) s += expf(v[i] - m);
  float l = m + logf(s);
#pragma unroll
  for (int i = 0; i < 4; i++) {
    *(float4*)&out[t * 16 + i * 4] =
        make_float4(v[i * 4 + 0] - l, v[i * 4 + 1] - l, v[i * 4 + 2] - l, v[i * 4 + 3] - l);
  }
}

extern "C" void kernel_launch(void* const* d_in, const int* in_sizes, int n_in,
                              void* d_out, int out_size, void* d_ws, size_t ws_size,
                              hipStream_t stream) {
  const float* x  = (const float*)d_in[0];
  const int*   ei = (const int*)d_in[1];
  const int*   et = (const int*)d_in[2];
  const float* ew = (const float*)d_in[3];
  const float* W1 = (const float*)d_in[4];
  const float* W2 = (const float*)d_in[5];
  float* out = (float*)d_out;
  float* ws = (float*)d_ws;

  // workspace layout (float-unit offsets; ~140 MB)
  int*    cnt    = (int*)ws;                    // 400000
  int*    off    = (int*)(ws + 400000);         // 400001 (+pad)
  int*    bsum   = (int*)(ws + 800004);         // 1563 (+pad)
  int*    bpre   = (int*)(ws + 801568);         // 1563 (+pad)
  int*    cursor = (int*)(ws + 803132);         // 400000
  int*    hist   = (int*)(ws + 1203132);        // 64
  int*    binCur = (int*)(ws + 1203196);        // 64
  int*    queue  = (int*)(ws + 1203260);        // 400000
  uint2*  rec    = (uint2*)(ws + 1603260);      // 640000 uint2
  ushort* xb     = (ushort*)(ws + 2883260);     // NN*DD bf16
  ushort* W1Tc   = (ushort*)(ws + 6083260);     // 128*1024 bf16
  ushort* W2T    = (ushort*)(ws + 6148796);     // 128*128 bf16
  ushort* Agg    = (ushort*)(ws + 6156988);     // NN*1024 bf16 (102.4 MB)
  ushort* H2     = (ushort*)(ws + 31756988);    // NN*DD bf16

  hipMemsetAsync(cnt, 0, (size_t)NBUCK * sizeof(int), stream);
  hipMemsetAsync(out, 0, (size_t)NN * NCLS * sizeof(float), stream);

  count_kernel<<<(EE + 255) / 256, 256, 0, stream>>>(ei, et, cnt);
  scan1_kernel<<<SCAN_NB, 256, 0, stream>>>(cnt, off, bsum);
  scan2_kernel<<<1, 256, 0, stream>>>(bsum, bpre);
  scan3_kernel<<<SCAN_NB, 256, 0, stream>>>(off, bpre, cursor, hist);
  bucket_kernel<<<(EE + 255) / 256, 256, 0, stream>>>(ei, et, ew, cursor, rec);

  hist_kernel<<<SCAN_NB, 256, 0, stream>>>(cnt, hist);
  scan64_kernel<<<1, 256, 0, stream>>>(hist, binCur);
  qbuild_kernel<<<SCAN_NB, 256, 0, stream>>>(cnt, binCur, queue);

  const int packN = XQ + NREL * DD * DD + DD * DD;
  pack_kernel<<<(packN + 255) / 256, 256, 0, stream>>>(x, W1, W2, xb, W1Tc, W2T);

  gather1_kernel<<<NBUCK / 64, 256, 0, stream>>>(off, rec, xb, queue, Agg);
  gemmfused_kernel<<<(NN + 63) / 64, 256, 0, stream>>>(Agg, W1Tc, W2T, H2);
  gather2_kernel<<<SCAN_NB, 256, 0, stream>>>(off, rec, H2, queue, out);
  lsm_kernel<<<(NN + 255) / 256, 256, 0, stream>>>(out);
}

// Round 9
// 293.244 us; speedup vs baseline: 2.0315x; 2.0315x over previous
//
#include <hip/hip_runtime.h>
#include <hip/hip_bf16.h>
#include <math.h>

#define NN 50000
#define EE 640000
#define DD 128
#define NREL 8
#define NCLS 16
#define NBUCK (NREL * NN)              // 400000 buckets, key = dst*8 + rel (dst-major)
#define SCAN_NB ((NBUCK + 255) / 256)  // 1563
#define NBIN 64

typedef __attribute__((ext_vector_type(8))) short short8;   // 8 bf16 = 4 VGPRs
typedef __attribute__((ext_vector_type(4))) float f32x4;    // MFMA acc

__device__ __forceinline__ float bflo(unsigned u) { return __uint_as_float(u << 16); }
__device__ __forceinline__ float bfhi(unsigned u) { return __uint_as_float(u & 0xffff0000u); }
__device__ __forceinline__ float bf2f(ushort u) { return __uint_as_float(((unsigned)u) << 16); }
__device__ __forceinline__ ushort f2b(float f) {  // RNE
  unsigned u = __float_as_uint(f);
  u += 0x7fff + ((u >> 16) & 1);
  return (ushort)(u >> 16);
}

// ---------- CSR build (key = dst*8 + rel) ----------

__global__ __launch_bounds__(256) void count_kernel(const int* __restrict__ ei,
                                                    const int* __restrict__ et,
                                                    int* __restrict__ cnt) {
  int t = blockIdx.x * 256 + threadIdx.x;
  if (t < EE) {
    int key = ei[EE + t] * NREL + et[t];
    atomicAdd(&cnt[key], 1);
  }
}

__global__ __launch_bounds__(256) void scan1_kernel(const int* __restrict__ cnt,
                                                    int* __restrict__ off,
                                                    int* __restrict__ bsum) {
  __shared__ int s[256];
  const int tid = threadIdx.x;
  const int i = blockIdx.x * 256 + tid;
  int v = (i < NBUCK) ? cnt[i] : 0;
  s[tid] = v;
  __syncthreads();
#pragma unroll
  for (int o = 1; o < 256; o <<= 1) {
    int t2 = (tid >= o) ? s[tid - o] : 0;
    __syncthreads();
    s[tid] += t2;
    __syncthreads();
  }
  if (i < NBUCK) off[i] = s[tid] - v;
  if (tid == 255) bsum[blockIdx.x] = s[255];
}

__global__ __launch_bounds__(256) void scan2_kernel(const int* __restrict__ bsum,
                                                    int* __restrict__ bpre) {
  __shared__ int s[256];
  __shared__ int carry;
  const int tid = threadIdx.x;
  if (tid == 0) carry = 0;
  __syncthreads();
  const int chunks = (SCAN_NB + 255) / 256;
  for (int c = 0; c < chunks; c++) {
    int idx = c * 256 + tid;
    int v = (idx < SCAN_NB) ? bsum[idx] : 0;
    s[tid] = v;
    __syncthreads();
#pragma unroll
    for (int o = 1; o < 256; o <<= 1) {
      int t2 = (tid >= o) ? s[tid - o] : 0;
      __syncthreads();
      s[tid] += t2;
      __syncthreads();
    }
    if (idx < SCAN_NB) bpre[idx] = carry + s[tid] - v;
    __syncthreads();
    if (tid == 255) carry += s[255];
    __syncthreads();
  }
}

// finalizes off, fills cursor, zeroes the degree-bin histogram
__global__ __launch_bounds__(256) void scan3_kernel(int* __restrict__ off,
                                                    const int* __restrict__ bpre,
                                                    int* __restrict__ cursor,
                                                    int* __restrict__ hist) {
  int i = blockIdx.x * 256 + threadIdx.x;
  if (i < NBUCK) {
    int o = off[i] + bpre[i >> 8];
    off[i] = o;
    cursor[i] = o;
  }
  if (i < NBIN) hist[i] = 0;
  if (i == 0) off[NBUCK] = EE;
}

// rec word0 = src | rel<<16 ; word1 = ew/cnt (pre-divided mean scale)
__global__ __launch_bounds__(256) void bucket_kernel(const int* __restrict__ ei,
                                                     const int* __restrict__ et,
                                                     const float* __restrict__ ew,
                                                     const int* __restrict__ cnt,
                                                     int* __restrict__ cursor,
                                                     uint2* __restrict__ rec) {
  int e = blockIdx.x * 256 + threadIdx.x;
  if (e >= EE) return;
  int r = et[e];
  int key = ei[EE + e] * NREL + r;
  float scale = ew[e] / fmaxf((float)cnt[key], 1.0f);
  int pos = atomicAdd(&cursor[key], 1);
  rec[pos] = make_uint2((unsigned)ei[e] | ((unsigned)r << 16), __float_as_uint(scale));
}

// ---------- node-degree counting sort -> vqueue ----------

__global__ __launch_bounds__(256) void vhist_kernel(const int* __restrict__ off,
                                                    int* __restrict__ hist) {
  __shared__ int lh[NBIN];
  const int tid = threadIdx.x;
  if (tid < NBIN) lh[tid] = 0;
  __syncthreads();
  int v = blockIdx.x * 256 + tid;
  if (v < NN) {
    int deg = off[v * NREL + NREL] - off[v * NREL];
    atomicAdd(&lh[min(deg, NBIN - 1)], 1);
  }
  __syncthreads();
  if (tid < NBIN && lh[tid] > 0) atomicAdd(&hist[tid], lh[tid]);
}

__global__ __launch_bounds__(256) void scan64_kernel(const int* __restrict__ hist,
                                                     int* __restrict__ binCur) {
  __shared__ int s[NBIN];
  const int tid = threadIdx.x;
  if (tid < NBIN) s[tid] = hist[tid];
  __syncthreads();
#pragma unroll
  for (int o = 1; o < NBIN; o <<= 1) {
    int t2 = (tid < NBIN && tid >= o) ? s[tid - o] : 0;
    __syncthreads();
    if (tid < NBIN) s[tid] += t2;
    __syncthreads();
  }
  if (tid < NBIN) binCur[tid] = s[tid] - hist[tid];
}

__global__ __launch_bounds__(256) void vqbuild_kernel(const int* __restrict__ off,
                                                      int* __restrict__ binCur,
                                                      int* __restrict__ vqueue) {
  __shared__ int lh[NBIN];
  __shared__ int lbase[NBIN];
  const int tid = threadIdx.x;
  const int v = blockIdx.x * 256 + tid;
  int bin = -1, lpos = 0;
  if (tid < NBIN) lh[tid] = 0;
  __syncthreads();
  if (v < NN) {
    int deg = off[v * NREL + NREL] - off[v * NREL];
    bin = min(deg, NBIN - 1);
    lpos = atomicAdd(&lh[bin], 1);
  }
  __syncthreads();
  if (tid < NBIN && lh[tid] > 0) lbase[tid] = atomicAdd(&binCur[tid], lh[tid]);
  __syncthreads();
  if (bin >= 0) vqueue[lbase[bin] + lpos] = v;
}

// ---------- pack x (bf16) + W1Tc + W2T ----------
// W1Tc[n*1024 + r*128 + k] = bf16(W1[r][k][n]); W2T[j*128 + k] = bf16(W2[j>>4][k][j&15])
#define XQ (NN * DD / 4)
__global__ __launch_bounds__(256) void pack_kernel(const float* __restrict__ x,
                                                   const float* __restrict__ W1,
                                                   const float* __restrict__ W2,
                                                   ushort* __restrict__ xb,
                                                   ushort* __restrict__ W1Tc,
                                                   ushort* __restrict__ W2T) {
  int t = blockIdx.x * 256 + threadIdx.x;
  if (t < XQ) {
    float4 v = *(const float4*)&x[(size_t)t * 4];
    *(ushort4*)&xb[(size_t)t * 4] = make_ushort4(f2b(v.x), f2b(v.y), f2b(v.z), f2b(v.w));
  } else if (t < XQ + NREL * DD * DD) {
    int t2 = t - XQ;
    int n = t2 >> 10, r = (t2 >> 7) & 7, k = t2 & 127;
    W1Tc[t2] = f2b(W1[r * 16384 + k * 128 + n]);
  } else if (t < XQ + NREL * DD * DD + DD * DD) {
    int t2 = t - XQ - NREL * DD * DD;
    int j = t2 >> 7, k = t2 & 127;
    W2T[t2] = f2b(W2[(j >> 4) * (DD * NCLS) + k * NCLS + (j & 15)]);
  }
}

// ---------- fused layer1+layer2: H2 = bf16( relu(gather(x) @ W1cat) @ W2T^T ) ----------
// Block = 64 nodes. Per relation r: register gather (4 thr/node x 32 cols, each
// thread an independent chain) -> bf16 tile in LDS -> MFMA. Then relu epilogue
// and the layer-2 GEMM on the in-LDS tile. A2 never touches HBM.
__global__ __launch_bounds__(256) void fused1_kernel(const int* __restrict__ off,
                                                     const uint2* __restrict__ rec,
                                                     const ushort* __restrict__ xb,
                                                     const ushort* __restrict__ W1Tc,
                                                     const ushort* __restrict__ W2T,
                                                     ushort* __restrict__ H2) {
  __shared__ ushort AsU[64 * 136];     // 17408 B
  __shared__ ushort Bs[128 * 136];     // 34816 B  (52224 total -> 3 blocks/CU)
  const int tid = threadIdx.x;
  const int m0 = blockIdx.x * 64;
  const int wave = tid >> 6, lane = tid & 63;
  const int lm = lane & 15, lkb = (lane >> 4) * 8;
  const int gn = tid >> 2;          // gather: node 0..63
  const int gc = (tid & 3) * 32;    // gather: col base
  const int v = m0 + gn;

  f32x4 acc[4][2];
#pragma unroll
  for (int m = 0; m < 4; m++)
#pragma unroll
    for (int j = 0; j < 2; j++) acc[m][j] = (f32x4){0.f, 0.f, 0.f, 0.f};

  for (int r = 0; r < NREL; r++) {
    __syncthreads();  // previous chunk's As/Bs reads complete
    // stage W1Tc slice for relation r
#pragma unroll
    for (int i = 0; i < 8; i++) {
      int seg = tid + i * 256;
      int row = seg >> 4, c8 = (seg & 15) * 8;
      *(uint4*)&Bs[row * 136 + c8] =
          *(const uint4*)&W1Tc[(size_t)row * 1024 + r * 128 + c8];
    }
    // register gather: fp32 accumulate 32 cols of node v, relation r
    float g[32];
#pragma unroll
    for (int j = 0; j < 32; j++) g[j] = 0.f;
    if (v < NN) {
      int b = v * NREL + r;
      int s = off[b], e = off[b + 1];
      for (int i = s; i < e; i++) {
        uint2 q = rec[i];
        float sc = __uint_as_float(q.y);     // pre-divided scale
        const ushort* xr = &xb[(size_t)(q.x & 0xffff) * DD + gc];
#pragma unroll
        for (int jj = 0; jj < 4; jj++) {
          uint4 h = *(const uint4*)&xr[jj * 8];
          float* gg = &g[jj * 8];
          gg[0] = fmaf(sc, bflo(h.x), gg[0]);
          gg[1] = fmaf(sc, bfhi(h.x), gg[1]);
          gg[2] = fmaf(sc, bflo(h.y), gg[2]);
          gg[3] = fmaf(sc, bfhi(h.y), gg[3]);
          gg[4] = fmaf(sc, bflo(h.z), gg[4]);
          gg[5] = fmaf(sc, bfhi(h.z), gg[5]);
          gg[6] = fmaf(sc, bflo(h.w), gg[6]);
          gg[7] = fmaf(sc, bfhi(h.w), gg[7]);
        }
      }
    }
#pragma unroll
    for (int jj = 0; jj < 4; jj++) {
      uint4 u;
      u.x = (unsigned)f2b(g[jj * 8 + 0]) | ((unsigned)f2b(g[jj * 8 + 1]) << 16);
      u.y = (unsigned)f2b(g[jj * 8 + 2]) | ((unsigned)f2b(g[jj * 8 + 3]) << 16);
      u.z = (unsigned)f2b(g[jj * 8 + 4]) | ((unsigned)f2b(g[jj * 8 + 5]) << 16);
      u.w = (unsigned)f2b(g[jj * 8 + 6]) | ((unsigned)f2b(g[jj * 8 + 7]) << 16);
      *(uint4*)&AsU[gn * 136 + gc + jj * 8] = u;
    }
    __syncthreads();
    // MFMA on this chunk
#pragma unroll
    for (int k0 = 0; k0 < 128; k0 += 32) {
      short8 a[4];
#pragma unroll
      for (int m = 0; m < 4; m++)
        a[m] = *(const short8*)&AsU[(m * 16 + lm) * 136 + k0 + lkb];
#pragma unroll
      for (int j = 0; j < 2; j++) {
        short8 b = *(const short8*)&Bs[((wave * 2 + j) * 16 + lm) * 136 + k0 + lkb];
#pragma unroll
        for (int m = 0; m < 4; m++)
          acc[m][j] = __builtin_amdgcn_mfma_f32_16x16x32_bf16(a[m], b, acc[m][j], 0, 0, 0);
      }
    }
  }

  // ---- epilogue 1: relu -> bf16 A2 tile in LDS ----
  __syncthreads();
  const int rquad = (lane >> 4) * 4;
#pragma unroll
  for (int m = 0; m < 4; m++)
#pragma unroll
    for (int j = 0; j < 2; j++)
#pragma unroll
      for (int i = 0; i < 4; i++)
        AsU[(m * 16 + rquad + i) * 136 + wave * 32 + j * 16 + lm] =
            f2b(fmaxf(acc[m][j][i], 0.f));
  __syncthreads();

  // ---- layer-2 GEMM on the in-LDS A2 tile ----
#pragma unroll
  for (int i = 0; i < 8; i++) {
    int seg = tid + i * 256;
    int row = seg >> 4, c8 = (seg & 15) * 8;
    *(uint4*)&Bs[row * 136 + c8] = *(const uint4*)&W2T[(size_t)row * DD + c8];
  }
  __syncthreads();
  f32x4 acc2[4][2];
#pragma unroll
  for (int m = 0; m < 4; m++)
#pragma unroll
    for (int j = 0; j < 2; j++) acc2[m][j] = (f32x4){0.f, 0.f, 0.f, 0.f};
#pragma unroll
  for (int k0 = 0; k0 < 128; k0 += 32) {
    short8 a[4];
#pragma unroll
    for (int m = 0; m < 4; m++)
      a[m] = *(const short8*)&AsU[(m * 16 + lm) * 136 + k0 + lkb];
#pragma unroll
    for (int j = 0; j < 2; j++) {
      short8 b = *(const short8*)&Bs[((wave * 2 + j) * 16 + lm) * 136 + k0 + lkb];
#pragma unroll
      for (int m = 0; m < 4; m++)
        acc2[m][j] = __builtin_amdgcn_mfma_f32_16x16x32_bf16(a[m], b, acc2[m][j], 0, 0, 0);
    }
  }
  __syncthreads();
#pragma unroll
  for (int m = 0; m < 4; m++)
#pragma unroll
    for (int j = 0; j < 2; j++)
#pragma unroll
      for (int i = 0; i < 4; i++)
        AsU[(m * 16 + rquad + i) * 136 + wave * 32 + j * 16 + lm] = f2b(acc2[m][j][i]);
  __syncthreads();
#pragma unroll
  for (int i = 0; i < 4; i++) {
    int seg = tid + i * 256;
    int row = seg >> 4, c8 = (seg & 15) * 8;
    int gr = m0 + row;
    if (gr < NN) *(uint4*)&H2[(size_t)gr * DD + c8] = *(const uint4*)&AsU[row * 136 + c8];
  }
}

// ---------- gather2 + log_softmax ----------
// 16 nodes/block from the degree-sorted queue; 16 lanes per node walk the node's
// single contiguous edge range (rel tag in rec); coalesced 32B H2 slices; no atomics.
__global__ __launch_bounds__(256) void gather2_kernel(const int* __restrict__ off,
                                                      const uint2* __restrict__ rec,
                                                      const ushort* __restrict__ H2,
                                                      const int* __restrict__ vqueue,
                                                      float* __restrict__ out) {
  const int tid = threadIdx.x;
  const int g = tid >> 4, c = tid & 15;
  const int qi = blockIdx.x * 16 + g;
  float acc = 0.f;
  int v = 0;
  if (qi < NN) {
    v = vqueue[qi];
    const int s = off[v * NREL], e = off[v * NREL + NREL];
    for (int j = s; j < e; j++) {
      uint2 q = rec[j];
      int src = q.x & 0xffff;
      int r = q.x >> 16;
      acc = fmaf(__uint_as_float(q.y),
                 bf2f(H2[(size_t)src * DD + r * NCLS + c]), acc);
    }
  }
  // log-softmax within the 16-lane group
  float m = acc;
#pragma unroll
  for (int mask = 8; mask >= 1; mask >>= 1) m = fmaxf(m, __shfl_xor(m, mask, 16));
  float ex = expf(acc - m);
#pragma unroll
  for (int mask = 8; mask >= 1; mask >>= 1) ex += __shfl_xor(ex, mask, 16);
  if (qi < NN) out[(size_t)v * NCLS + c] = acc - m - logf(ex);
}

extern "C" void kernel_launch(void* const* d_in, const int* in_sizes, int n_in,
                              void* d_out, int out_size, void* d_ws, size_t ws_size,
                              hipStream_t stream) {
  const float* x  = (const float*)d_in[0];
  const int*   ei = (const int*)d_in[1];
  const int*   et = (const int*)d_in[2];
  const float* ew = (const float*)d_in[3];
  const float* W1 = (const float*)d_in[4];
  const float* W2 = (const float*)d_in[5];
  float* out = (float*)d_out;
  float* ws = (float*)d_ws;

  // workspace layout (float-unit offsets; ~36 MB)
  int*    cnt    = (int*)ws;                    // 400000
  int*    off    = (int*)(ws + 400000);         // 400001 (+pad)
  int*    bsum   = (int*)(ws + 800004);         // 1563 (+pad)
  int*    bpre   = (int*)(ws + 801568);         // 1563 (+pad)
  int*    cursor = (int*)(ws + 803132);         // 400000
  int*    hist   = (int*)(ws + 1203132);        // 64
  int*    binCur = (int*)(ws + 1203196);        // 64
  int*    vqueue = (int*)(ws + 1203260);        // 50000
  uint2*  rec    = (uint2*)(ws + 1253260);      // 640000 uint2
  ushort* xb     = (ushort*)(ws + 2533260);     // NN*DD bf16
  ushort* W1Tc   = (ushort*)(ws + 5733260);     // 128*1024 bf16
  ushort* W2T    = (ushort*)(ws + 5798796);     // 128*128 bf16
  ushort* H2     = (ushort*)(ws + 5806988);     // NN*DD bf16

  hipMemsetAsync(cnt, 0, (size_t)NBUCK * sizeof(int), stream);

  count_kernel<<<(EE + 255) / 256, 256, 0, stream>>>(ei, et, cnt);
  scan1_kernel<<<SCAN_NB, 256, 0, stream>>>(cnt, off, bsum);
  scan2_kernel<<<1, 256, 0, stream>>>(bsum, bpre);
  scan3_kernel<<<SCAN_NB, 256, 0, stream>>>(off, bpre, cursor, hist);
  bucket_kernel<<<(EE + 255) / 256, 256, 0, stream>>>(ei, et, ew, cnt, cursor, rec);

  vhist_kernel<<<(NN + 255) / 256, 256, 0, stream>>>(off, hist);
  scan64_kernel<<<1, 256, 0, stream>>>(hist, binCur);
  vqbuild_kernel<<<(NN + 255) / 256, 256, 0, stream>>>(off, binCur, vqueue);

  const int packN = XQ + NREL * DD * DD + DD * DD;
  pack_kernel<<<(packN + 255) / 256, 256, 0, stream>>>(x, W1, W2, xb, W1Tc, W2T);

  fused1_kernel<<<(NN + 63) / 64, 256, 0, stream>>>(off, rec, xb, W1Tc, W2T, H2);
  gather2_kernel<<<(NN + 15) / 16, 256, 0, stream>>>(off, rec, H2, vqueue, out);
}